// Round 2
// baseline (609.619 us; speedup 1.0000x reference)
//
#include <hip/hip_runtime.h>

// Per row (64 floats of exact {0,1}):
//   e     = bits x[1..11] (x[1]=MSB), d = (e-1023) & 2047
//   mant6 = bits x[12..17] (x[12]=MSB)
//   low6  = (d<=5) ? (((0x40|mant6)<<d)>>6)&63 : 0
//   out[j] = bit (5-j) of low6, j=0..5
//
// Coalescing strategy: block=256 threads handles 256 rows.
//  - Stage cols 0..19 of each row (5 float4 = 80B) into LDS with linearized
//    (row,quad) indexing so consecutive lanes hit consecutive 16B chunks.
//  - LDS input stride 21 floats (odd) -> conflict-free per-row scalar reads.
//  - Compute one row per thread; results into packed LDS out buffer.
//  - Copy out as fully-coalesced float2 stores.

#define ROWS 256
#define STR  21

__global__ __launch_bounds__(256) void extract_low6_kernel(
    const float* __restrict__ x, float* __restrict__ out, int nrows) {
    __shared__ float sin_[ROWS * STR];   // cols 0..19 per row (+1 pad word)
    __shared__ float sout[ROWS * 6];

    const int t = threadIdx.x;
    const int rowBase = blockIdx.x * ROWS;
    int rem = nrows - rowBase;
    if (rem > ROWS) rem = ROWS;

    // ---- stage: cols 0..19 of each row, coalesced ----
    const float* gbase = x + (size_t)rowBase * 64;
    #pragma unroll
    for (int k = 0; k < 5; ++k) {
        int idx  = k * 256 + t;        // 0..1279
        int row  = idx / 5;            // const-div -> mul/shift
        int quad = idx - row * 5;      // 0..4
        if (row < rem) {
            float4 v = *(const float4*)(gbase + row * 64 + quad * 4);
            float* d = &sin_[row * STR + quad * 4];
            d[0] = v.x; d[1] = v.y; d[2] = v.z; d[3] = v.w;
        }
    }
    __syncthreads();

    // ---- compute: one thread per row ----
    if (t < rem) {
        const float* s = &sin_[t * STR];
        int e = 0;
        #pragma unroll
        for (int i = 0; i < 11; ++i)
            e |= (int)((__float_as_uint(s[1 + i]) >> 23) & 1u) << (10 - i);
        int mant = 0;
        #pragma unroll
        for (int i = 0; i < 6; ++i)
            mant |= (int)((__float_as_uint(s[12 + i]) >> 23) & 1u) << (5 - i);
        unsigned d = (unsigned)(e - 1023) & 2047u;
        int low6 = (d <= 5u) ? (((0x40 | mant) << d) >> 6) & 63 : 0;
        float* o = &sout[t * 6];
        #pragma unroll
        for (int j = 0; j < 6; ++j)
            o[j] = (float)((low6 >> (5 - j)) & 1);
    }
    __syncthreads();

    // ---- copy out: fully coalesced float2 ----
    float* obase = out + (size_t)rowBase * 6;
    const int nw = rem * 6;            // valid floats (always even)
    #pragma unroll
    for (int k = 0; k < 3; ++k) {
        int idx = k * 256 + t;         // float2 index 0..767
        if (idx * 2 < nw)
            *(float2*)(obase + idx * 2) = *(float2*)(&sout[idx * 2]);
    }
}

extern "C" void kernel_launch(void* const* d_in, const int* in_sizes, int n_in,
                              void* d_out, int out_size, void* d_ws, size_t ws_size,
                              hipStream_t stream) {
    const float* x = (const float*)d_in[0];
    float* out = (float*)d_out;
    int nrows = in_sizes[0] / 64;      // 2,000,000
    int grid = (nrows + ROWS - 1) / ROWS;
    extract_low6_kernel<<<grid, 256, 0, stream>>>(x, out, nrows);
}

// Round 3
// 608.327 us; speedup vs baseline: 1.0021x; 1.0021x over previous
//
#include <hip/hip_runtime.h>
#include <stdint.h>

// Per row (64 floats of exact {0,1}):
//   e = bits x[1..11] (x[1]=MSB), d = (e-1023)&2047, mant6 = bits x[12..17]
//   low6 = (d<=5) ? (((0x40|mant6)<<d)>>6)&63 : 0 ; out = 6 bits MSB-first.
//
// Staging: async global->LDS (global_load_lds, 16B/lane). idx = k*256+t maps
// to (row=idx/5, quad=idx%5); LDS dst is wave-uniform base + lane*16, giving a
// packed 80B/row layout (stride 20 floats). Compute reads use ds_read_b128:
// bank starts (20t+4q)%32 tile all 32 banks per 8-lane group -> conflict-free.

#define ROWS 256

typedef __attribute__((address_space(3))) uint32_t lds_u32_t;
typedef __attribute__((address_space(1))) const uint32_t glb_u32_t;

__global__ __launch_bounds__(256) void extract_low6_kernel(
    const float* __restrict__ x, float* __restrict__ out, int nrows) {
    __shared__ uint32_t sin_[ROWS * 20];   // cols 0..19 per row, packed 80B/row
    __shared__ float sout[ROWS * 6];

    const int t = threadIdx.x;
    const int rowBase = blockIdx.x * ROWS;
    int rem = nrows - rowBase;
    if (rem > ROWS) rem = ROWS;

    const uint32_t* gbase = (const uint32_t*)(x + (size_t)rowBase * 64);

    // ---- stage: 5 async 16B/lane global->LDS loads, all in flight ----
    #pragma unroll
    for (int k = 0; k < 5; ++k) {
        int idx  = k * 256 + t;          // 0..1279
        int row  = idx / 5;
        int quad = idx - row * 5;        // 0..4
        if (row >= rem) row = 0;         // tail block: keep address valid (data unused)
        const uint32_t* gaddr = gbase + row * 64 + quad * 4;
        // LDS dst chunk = idx (wave-uniform base + lane*16)
        lds_u32_t* laddr = (lds_u32_t*)&sin_[(k * 256 + (t & ~63)) * 4];
        __builtin_amdgcn_global_load_lds((glb_u32_t*)gaddr, laddr, 16, 0, 0);
    }
    __syncthreads();   // drains vmcnt (global_load_lds) before LDS reads

    // ---- compute: one thread per row, conflict-free b128 LDS reads ----
    if (t < rem) {
        const uint32_t* s = &sin_[t * 20];
        uint4 v0 = *(const uint4*)(s + 0);    // cols 0..3
        uint4 v1 = *(const uint4*)(s + 4);    // cols 4..7
        uint4 v2 = *(const uint4*)(s + 8);    // cols 8..11
        uint4 v3 = *(const uint4*)(s + 12);   // cols 12..15
        uint2 v4 = *(const uint2*)(s + 16);   // cols 16..17

        // values are exactly 0.0f/1.0f -> bit 23 of the float encoding is the bit
        int e = 0;
        e |= (int)((v0.y >> 23) & 1u) << 10;
        e |= (int)((v0.z >> 23) & 1u) << 9;
        e |= (int)((v0.w >> 23) & 1u) << 8;
        e |= (int)((v1.x >> 23) & 1u) << 7;
        e |= (int)((v1.y >> 23) & 1u) << 6;
        e |= (int)((v1.z >> 23) & 1u) << 5;
        e |= (int)((v1.w >> 23) & 1u) << 4;
        e |= (int)((v2.x >> 23) & 1u) << 3;
        e |= (int)((v2.y >> 23) & 1u) << 2;
        e |= (int)((v2.z >> 23) & 1u) << 1;
        e |= (int)((v2.w >> 23) & 1u);

        int mant = 0;
        mant |= (int)((v3.x >> 23) & 1u) << 5;
        mant |= (int)((v3.y >> 23) & 1u) << 4;
        mant |= (int)((v3.z >> 23) & 1u) << 3;
        mant |= (int)((v3.w >> 23) & 1u) << 2;
        mant |= (int)((v4.x >> 23) & 1u) << 1;
        mant |= (int)((v4.y >> 23) & 1u);

        unsigned d = (unsigned)(e - 1023) & 2047u;
        int low6 = (d <= 5u) ? (((0x40 | mant) << d) >> 6) & 63 : 0;

        float* o = &sout[t * 6];
        #pragma unroll
        for (int j = 0; j < 6; ++j)
            o[j] = (float)((low6 >> (5 - j)) & 1);
    }
    __syncthreads();

    // ---- copy out: fully coalesced float2 stores ----
    float* obase = out + (size_t)rowBase * 6;
    const int nw = rem * 6;              // valid floats (always even)
    #pragma unroll
    for (int k = 0; k < 3; ++k) {
        int idx = k * 256 + t;           // float2 index 0..767
        if (idx * 2 < nw)
            *(float2*)(obase + idx * 2) = *(float2*)(&sout[idx * 2]);
    }
}

extern "C" void kernel_launch(void* const* d_in, const int* in_sizes, int n_in,
                              void* d_out, int out_size, void* d_ws, size_t ws_size,
                              hipStream_t stream) {
    const float* x = (const float*)d_in[0];
    float* out = (float*)d_out;
    int nrows = in_sizes[0] / 64;        // 2,000,000
    int grid = (nrows + ROWS - 1) / ROWS;
    extract_low6_kernel<<<grid, 256, 0, stream>>>(x, out, nrows);
}